// Round 7
// baseline (1184.125 us; speedup 1.0000x reference)
//
#include <hip/hip_runtime.h>
#include <math.h>

#define NTOK 16384      // b*n = 8*2048
#define NPB  2048       // tokens per batch
#define DDIM 1024
#define NEXP 64
#define CAP  80
#define ROWF 5120       // NEXP*CAP floats per token row
#define SOUT 83886080LL // NTOK*NEXP*CAP

typedef float vf4 __attribute__((ext_vector_type(4)));
typedef float vf2 __attribute__((ext_vector_type(2)));

// workspace layout (bytes)
#define OFF_ROUTE  0                        // NTOK int (idx1 | idx2<<8 | keep2<<16)
#define OFF_POS1   (OFF_ROUTE + NTOK*4)     // NTOK int
#define OFF_POS2   (OFF_POS1  + NTOK*4)     // NTOK int
#define OFF_CNT1   (OFF_POS2  + NTOK*4)     // 512 int
#define OFF_PART   (OFF_CNT1  + 2048)       // 512*64 float per-block raw-gate sums
#define OFF_G12    (OFF_PART  + 131072)     // NTOK float2

// K1: fused logits GEMM, 512 single-wave blocks (2 blocks/CU), each 32 tok x
// 64 exp, 8x4 per thread. a from LDS (2 ds_read_b128/k), b (w) straight from
// global (L1/L2-hot, 256 KB). Token-paired vf2 accumulate for v_pk_fma_f32.
__global__ __launch_bounds__(64) void k_gate(
    const float* __restrict__ x, const float* __restrict__ w,
    const float* __restrict__ noise,
    int* __restrict__ route, float2* __restrict__ g12,
    float* __restrict__ part)
{
    __shared__ float xs[64][36];   // xs[k][token], row 144 B (16B-aligned)
    __shared__ float lg[32][65];   // logits

    const int lane = threadIdx.x;
    const int tok0 = blockIdx.x * 32;
    const int tt = lane >> 4;      // token-group (8 tokens)
    const int tx = lane & 15;      // expert quad
    const int st = lane >> 1, sh = lane & 1;  // staging: token, k-half

    vf2 acc[4][4] = {};            // 4 token-pairs x 4 experts

    const float* xb = x + (size_t)tok0 * DDIM;

    float4 px[8];
    #pragma unroll
    for (int r = 0; r < 8; ++r)
        px[r] = *(const float4*)(xb + (size_t)st * DDIM + (sh * 8 + r) * 4);

    for (int k0 = 0; k0 < DDIM; k0 += 64) {
        #pragma unroll
        for (int r = 0; r < 8; ++r) {
            int kk = (sh * 8 + r) * 4;
            xs[kk+0][st] = px[r].x; xs[kk+1][st] = px[r].y;
            xs[kk+2][st] = px[r].z; xs[kk+3][st] = px[r].w;
        }
        __syncthreads();

        if (k0 + 64 < DDIM) {   // register-prefetch next x tile
            #pragma unroll
            for (int r = 0; r < 8; ++r)
                px[r] = *(const float4*)(xb + (size_t)st * DDIM + k0 + 64 + (sh * 8 + r) * 4);
        }

        const float* wk = w + (size_t)k0 * NEXP + tx * 4;
        #pragma unroll 8
        for (int k = 0; k < 64; ++k) {
            vf4 aA = *(const vf4*)&xs[k][tt * 8];
            vf4 aB = *(const vf4*)&xs[k][tt * 8 + 4];
            float4 bb = *(const float4*)(wk + (size_t)k * NEXP);
            vf2 a2[4] = {{aA.x, aA.y}, {aA.z, aA.w}, {aB.x, aB.y}, {aB.z, aB.w}};
            float bv[4] = {bb.x, bb.y, bb.z, bb.w};
            #pragma unroll
            for (int p = 0; p < 4; ++p)
                #pragma unroll
                for (int j = 0; j < 4; ++j) {
                    vf2 b2 = {bv[j], bv[j]};
                    acc[p][j] += a2[p] * b2;
                }
        }
        __syncthreads();
    }

    #pragma unroll
    for (int p = 0; p < 4; ++p)
        #pragma unroll
        for (int j = 0; j < 4; ++j) {
            lg[tt * 8 + p * 2 + 0][tx * 4 + j] = acc[p][j].x;
            lg[tt * 8 + p * 2 + 1][tx * 4 + j] = acc[p][j].y;
        }
    __syncthreads();

    // softmax + top2: lane == expert, the wave walks 32 tokens
    float gsum_acc = 0.f;
    for (int t = 0; t < 32; ++t) {
        float v = lg[t][lane];

        float m = v; int mi = lane;
        #pragma unroll
        for (int off = 32; off; off >>= 1) {
            float ov = __shfl_xor(m, off, 64);
            int   oi = __shfl_xor(mi, off, 64);
            if (ov > m || (ov == m && oi < mi)) { m = ov; mi = oi; }
        }
        float v2 = (lane == mi) ? -INFINITY : v;
        float m2 = v2; int mi2 = lane;
        #pragma unroll
        for (int off = 32; off; off >>= 1) {
            float ov = __shfl_xor(m2, off, 64);
            int   oi = __shfl_xor(mi2, off, 64);
            if (ov > m2 || (ov == m2 && oi < mi2)) { m2 = ov; mi2 = oi; }
        }
        float ex = expf(v - m);
        float s = ex;
        #pragma unroll
        for (int off = 32; off; off >>= 1) s += __shfl_xor(s, off, 64);

        float inv   = 1.0f / s;
        float gate1 = inv;
        float gate2 = expf(m2 - m) * inv;
        gsum_acc += ex * inv;

        float denom = gate1 + gate2 + 1e-9f;
        float g1n = gate1 / denom;
        float g2n = gate2 / denom;

        int gt = tok0 + t;
        if (lane == 0) {
            float u = noise[gt];
            int k2 = (u < (g2n / 0.2f)) ? 1 : 0;
            route[gt] = mi | (mi2 << 8) | (k2 << 16);
            g12[gt] = make_float2(g1n, g2n);
        }
    }

    part[blockIdx.x * 64 + lane] = gsum_acc;
}

// K2: 3-phase position scan per batch (one 256-thread block per batch):
// A) per-64-token-tile expert histograms, B) exclusive prefix over tiles,
// C) positional rewrite with per-tile bases.
__global__ __launch_bounds__(256) void k_pos(
    const int* __restrict__ route,
    int* __restrict__ pos1, int* __restrict__ pos2raw,
    int* __restrict__ cnt1tot)
{
    const int b    = blockIdx.x;
    const int tid  = threadIdx.x;
    const int lane = tid & 63, wv = tid >> 6;
    __shared__ int sr[NPB];
    __shared__ int h1[32][64], h2[32][64];

    for (int i = tid; i < NPB; i += 256) sr[i] = route[b * NPB + i];
    __syncthreads();

    for (int tau = wv; tau < 32; tau += 4) {
        int c1 = 0, c2 = 0;
        const int* p = &sr[tau * 64];
        #pragma unroll 8
        for (int j = 0; j < 64; ++j) {
            int r = p[j];
            c1 += ((r & 255) == lane);
            c2 += ((r >> 16) && (((r >> 8) & 255) == lane));
        }
        h1[tau][lane] = c1; h2[tau][lane] = c2;
    }
    __syncthreads();

    if (tid < 64) {
        int run = 0;
        #pragma unroll 8
        for (int tau = 0; tau < 32; ++tau) {
            int t = h1[tau][tid]; h1[tau][tid] = run; run += t;
        }
        cnt1tot[b * NEXP + tid] = run;   // pre-capacity top1 total
    } else if (tid < 128) {
        int e = tid - 64, run = 0;
        #pragma unroll 8
        for (int tau = 0; tau < 32; ++tau) {
            int t = h2[tau][e]; h2[tau][e] = run; run += t;
        }
    }
    __syncthreads();

    for (int tau = wv; tau < 32; tau += 4) {
        int c1 = h1[tau][lane], c2 = h2[tau][lane];
        const int* p = &sr[tau * 64];
        const int gbase = b * NPB + tau * 64;
        #pragma unroll 4
        for (int j = 0; j < 64; ++j) {
            int r = p[j];
            if ((r & 255) == lane) pos1[gbase + j] = c1++;
            if ((r >> 16) && (((r >> 8) & 255) == lane)) pos2raw[gbase + j] = c2++;
        }
    }
}

// K3: single streaming pass writes BOTH halves (dispatch + combine) for 4
// tokens per block; zero fast-path; block 4096 computes the loss.
__global__ __launch_bounds__(256) void k_out(
    const int* __restrict__ route,
    const int* __restrict__ pos1, const int* __restrict__ pos2raw,
    const int* __restrict__ cnt1tot,
    const float2* __restrict__ g12, const float* __restrict__ part,
    float* __restrict__ out)
{
    const int tid = threadIdx.x;
    const int bid = blockIdx.x;

    if (bid == 4096) {
        __shared__ float red[4];
        float v = 0.f;
        for (int p = tid; p < 512; p += 256) {
            int b = p >> 6, e = p & 63;
            float s = 0.f;
            #pragma unroll 8
            for (int c = 0; c < 64; ++c) s += part[((b << 6) + c) * 64 + e];
            v += s * (float)cnt1tot[p];
        }
        #pragma unroll
        for (int off = 32; off; off >>= 1) v += __shfl_xor(v, off, 64);
        if ((tid & 63) == 0) red[tid >> 6] = v;
        __syncthreads();
        if (tid == 0)
            out[2 * SOUT] = (red[0] + red[1] + red[2] + red[3]) * (1.0f / 524288.0f);
        return;
    }

    const int tg = bid * 4;

    __shared__ int   se[4][2];
    __shared__ float sv[4][2];

    if (tid < 4) {
        int t = tg + tid;
        int b = t >> 11;
        int r  = route[t];
        int i1 = r & 255, i2 = (r >> 8) & 255, k2 = (r >> 16);
        float2 g = g12[t];

        int p1 = pos1[t];
        se[tid][0] = (p1 < CAP) ? (i1 * CAP + p1) : -1;
        sv[tid][0] = g.x;

        int e2 = -1;
        if (k2) {
            int m1c = min(cnt1tot[(b << 6) + i2], CAP);
            int p2  = pos2raw[t] + m1c;
            if (p2 < CAP) e2 = i2 * CAP + p2;
        }
        se[tid][1] = e2;
        sv[tid][1] = g.y;
    }
    __syncthreads();

    vf4* dbase = (vf4*)(out + (size_t)tg * ROWF);
    vf4* cbase = (vf4*)(out + (size_t)SOUT + (size_t)tg * ROWF);
    #pragma unroll
    for (int t = 0; t < 4; ++t) {
        const int   e1 = se[t][0], e2 = se[t][1];
        const float v1 = sv[t][0], v2 = sv[t][1];
        const int   q1 = e1 >> 2, q2 = e2 >> 2;   // vf4 slot containing e1/e2
        vf4* pd = dbase + (size_t)t * (ROWF / 4);
        vf4* pc = cbase + (size_t)t * (ROWF / 4);
        for (int s = tid; s < ROWF / 4; s += 256) {
            vf4 d = {0.f, 0.f, 0.f, 0.f};
            vf4 c = {0.f, 0.f, 0.f, 0.f};
            if (s == q1) { d[e1 & 3] = 1.f; c[e1 & 3] = v1; }   // rare
            if (s == q2) { d[e2 & 3] = 1.f; c[e2 & 3] = v2; }   // rare
            __builtin_nontemporal_store(d, pd + s);
            __builtin_nontemporal_store(c, pc + s);
        }
    }
}

extern "C" void kernel_launch(void* const* d_in, const int* in_sizes, int n_in,
                              void* d_out, int out_size, void* d_ws, size_t ws_size,
                              hipStream_t stream) {
    (void)in_sizes; (void)n_in; (void)ws_size; (void)out_size;
    const float* x     = (const float*)d_in[0];
    const float* w     = (const float*)d_in[1];
    const float* noise = (const float*)d_in[2];
    float* out = (float*)d_out;
    char*  ws  = (char*)d_ws;

    int*    route   = (int*)   (ws + OFF_ROUTE);
    int*    pos1    = (int*)   (ws + OFF_POS1);
    int*    pos2raw = (int*)   (ws + OFF_POS2);
    int*    cnt1tot = (int*)   (ws + OFF_CNT1);
    float*  part    = (float*) (ws + OFF_PART);
    float2* g12     = (float2*)(ws + OFF_G12);

    k_gate<<<dim3(NTOK / 32), dim3(64), 0, stream>>>(
        x, w, noise, route, g12, part);
    k_pos<<<dim3(8), dim3(256), 0, stream>>>(
        route, pos1, pos2raw, cnt1tot);
    k_out<<<dim3(4097), dim3(256), 0, stream>>>(
        route, pos1, pos2raw, cnt1tot, g12, part, out);
}

// Round 8
// 866.260 us; speedup vs baseline: 1.3669x; 1.3669x over previous
//
#include <hip/hip_runtime.h>
#include <math.h>

#define NTOK 16384      // b*n = 8*2048
#define NPB  2048       // tokens per batch
#define DDIM 1024
#define NEXP 64
#define CAP  80
#define ROWF 5120       // NEXP*CAP floats per token row
#define SOUT 83886080LL // NTOK*NEXP*CAP

typedef float vf4 __attribute__((ext_vector_type(4)));

// workspace layout (bytes)
#define OFF_ROUTE  0                        // NTOK int (idx1 | idx2<<8 | keep2<<16)
#define OFF_POS1   (OFF_ROUTE + NTOK*4)     // NTOK int
#define OFF_POS2   (OFF_POS1  + NTOK*4)     // NTOK int
#define OFF_CNT1   (OFF_POS2  + NTOK*4)     // 512 int
#define OFF_PART   (OFF_CNT1  + 2048)       // 512*64 float per-block raw-gate sums
#define OFF_G12    (OFF_PART  + 131072)     // NTOK float2

// K1: GEMV-style fused gate. lane == expert; each wave owns 8 tokens.
// x[t][k] is wave-uniform -> scalar loads (SGPR broadcast into v_fma);
// w[k][lane] is lane-coalesced and L1/L2-hot. No LDS in the main loop.
// 512 blocks x 256 threads = 8 waves/CU.
__global__ __launch_bounds__(256) void k_gate(
    const float* __restrict__ x, const float* __restrict__ w,
    const float* __restrict__ noise,
    int* __restrict__ route, float2* __restrict__ g12,
    float* __restrict__ part)
{
    __shared__ float sG[4][64];
    const int tid  = threadIdx.x;
    const int lane = tid & 63;
    const int wv   = __builtin_amdgcn_readfirstlane(tid >> 6);
    const int tok0 = blockIdx.x * 32 + wv * 8;   // this wave's 8 tokens
    const float* xb = x + (size_t)tok0 * DDIM;   // wave-uniform base

    float acc[8] = {0.f, 0.f, 0.f, 0.f, 0.f, 0.f, 0.f, 0.f};

    for (int k0 = 0; k0 < DDIM; k0 += 8) {
        float wr[8];
        #pragma unroll
        for (int j = 0; j < 8; ++j)
            wr[j] = w[(size_t)(k0 + j) * NEXP + lane];   // coalesced, cached
        #pragma unroll
        for (int t = 0; t < 8; ++t) {
            #pragma unroll
            for (int j = 0; j < 8; ++j)
                acc[t] = fmaf(xb[(size_t)t * DDIM + k0 + j], wr[j], acc[t]);
        }
    }

    // softmax + top2 per token, straight from registers
    float gsum_acc = 0.f;
    #pragma unroll
    for (int t = 0; t < 8; ++t) {
        float v = acc[t];

        float m = v; int mi = lane;
        #pragma unroll
        for (int off = 32; off; off >>= 1) {
            float ov = __shfl_xor(m, off, 64);
            int   oi = __shfl_xor(mi, off, 64);
            if (ov > m || (ov == m && oi < mi)) { m = ov; mi = oi; }
        }
        float v2 = (lane == mi) ? -INFINITY : v;
        float m2 = v2; int mi2 = lane;
        #pragma unroll
        for (int off = 32; off; off >>= 1) {
            float ov = __shfl_xor(m2, off, 64);
            int   oi = __shfl_xor(mi2, off, 64);
            if (ov > m2 || (ov == m2 && oi < mi2)) { m2 = ov; mi2 = oi; }
        }
        float ex = expf(v - m);
        float s = ex;
        #pragma unroll
        for (int off = 32; off; off >>= 1) s += __shfl_xor(s, off, 64);

        float inv   = 1.0f / s;
        float gate1 = inv;
        float gate2 = expf(m2 - m) * inv;
        gsum_acc += ex * inv;

        float denom = gate1 + gate2 + 1e-9f;
        float g1n = gate1 / denom;
        float g2n = gate2 / denom;

        int gt = tok0 + t;
        if (lane == 0) {
            float u = noise[gt];
            int k2 = (u < (g2n / 0.2f)) ? 1 : 0;
            route[gt] = mi | (mi2 << 8) | (k2 << 16);
            g12[gt] = make_float2(g1n, g2n);
        }
    }

    sG[wv][lane] = gsum_acc;
    __syncthreads();
    if (tid < 64)
        part[blockIdx.x * 64 + tid] =
            sG[0][tid] + sG[1][tid] + sG[2][tid] + sG[3][tid];
}

// K2: 3-phase position scan per batch (one 256-thread block per batch):
// A) per-64-token-tile expert histograms, B) exclusive prefix over tiles,
// C) positional rewrite with per-tile bases.
__global__ __launch_bounds__(256) void k_pos(
    const int* __restrict__ route,
    int* __restrict__ pos1, int* __restrict__ pos2raw,
    int* __restrict__ cnt1tot)
{
    const int b    = blockIdx.x;
    const int tid  = threadIdx.x;
    const int lane = tid & 63, wv = tid >> 6;
    __shared__ int sr[NPB];
    __shared__ int h1[32][64], h2[32][64];

    for (int i = tid; i < NPB; i += 256) sr[i] = route[b * NPB + i];
    __syncthreads();

    for (int tau = wv; tau < 32; tau += 4) {
        int c1 = 0, c2 = 0;
        const int* p = &sr[tau * 64];
        #pragma unroll 8
        for (int j = 0; j < 64; ++j) {
            int r = p[j];
            c1 += ((r & 255) == lane);
            c2 += ((r >> 16) && (((r >> 8) & 255) == lane));
        }
        h1[tau][lane] = c1; h2[tau][lane] = c2;
    }
    __syncthreads();

    if (tid < 64) {
        int run = 0;
        #pragma unroll 8
        for (int tau = 0; tau < 32; ++tau) {
            int t = h1[tau][tid]; h1[tau][tid] = run; run += t;
        }
        cnt1tot[b * NEXP + tid] = run;   // pre-capacity top1 total
    } else if (tid < 128) {
        int e = tid - 64, run = 0;
        #pragma unroll 8
        for (int tau = 0; tau < 32; ++tau) {
            int t = h2[tau][e]; h2[tau][e] = run; run += t;
        }
    }
    __syncthreads();

    for (int tau = wv; tau < 32; tau += 4) {
        int c1 = h1[tau][lane], c2 = h2[tau][lane];
        const int* p = &sr[tau * 64];
        const int gbase = b * NPB + tau * 64;
        #pragma unroll 4
        for (int j = 0; j < 64; ++j) {
            int r = p[j];
            if ((r & 255) == lane) pos1[gbase + j] = c1++;
            if ((r >> 16) && (((r >> 8) & 255) == lane)) pos2raw[gbase + j] = c2++;
        }
    }
}

// K3: single streaming pass writes BOTH halves (dispatch + combine) for 4
// tokens per block; zero fast-path; block 4096 computes the loss.
__global__ __launch_bounds__(256) void k_out(
    const int* __restrict__ route,
    const int* __restrict__ pos1, const int* __restrict__ pos2raw,
    const int* __restrict__ cnt1tot,
    const float2* __restrict__ g12, const float* __restrict__ part,
    float* __restrict__ out)
{
    const int tid = threadIdx.x;
    const int bid = blockIdx.x;

    if (bid == 4096) {
        __shared__ float red[4];
        float v = 0.f;
        for (int p = tid; p < 512; p += 256) {
            int b = p >> 6, e = p & 63;
            float s = 0.f;
            #pragma unroll 8
            for (int c = 0; c < 64; ++c) s += part[((b << 6) + c) * 64 + e];
            v += s * (float)cnt1tot[p];
        }
        #pragma unroll
        for (int off = 32; off; off >>= 1) v += __shfl_xor(v, off, 64);
        if ((tid & 63) == 0) red[tid >> 6] = v;
        __syncthreads();
        if (tid == 0)
            out[2 * SOUT] = (red[0] + red[1] + red[2] + red[3]) * (1.0f / 524288.0f);
        return;
    }

    const int tg = bid * 4;

    __shared__ int   se[4][2];
    __shared__ float sv[4][2];

    if (tid < 4) {
        int t = tg + tid;
        int b = t >> 11;
        int r  = route[t];
        int i1 = r & 255, i2 = (r >> 8) & 255, k2 = (r >> 16);
        float2 g = g12[t];

        int p1 = pos1[t];
        se[tid][0] = (p1 < CAP) ? (i1 * CAP + p1) : -1;
        sv[tid][0] = g.x;

        int e2 = -1;
        if (k2) {
            int m1c = min(cnt1tot[(b << 6) + i2], CAP);
            int p2  = pos2raw[t] + m1c;
            if (p2 < CAP) e2 = i2 * CAP + p2;
        }
        se[tid][1] = e2;
        sv[tid][1] = g.y;
    }
    __syncthreads();

    vf4* dbase = (vf4*)(out + (size_t)tg * ROWF);
    vf4* cbase = (vf4*)(out + (size_t)SOUT + (size_t)tg * ROWF);
    #pragma unroll
    for (int t = 0; t < 4; ++t) {
        const int   e1 = se[t][0], e2 = se[t][1];
        const float v1 = sv[t][0], v2 = sv[t][1];
        const int   q1 = e1 >> 2, q2 = e2 >> 2;   // vf4 slot containing e1/e2
        vf4* pd = dbase + (size_t)t * (ROWF / 4);
        vf4* pc = cbase + (size_t)t * (ROWF / 4);
        for (int s = tid; s < ROWF / 4; s += 256) {
            vf4 d = {0.f, 0.f, 0.f, 0.f};
            vf4 c = {0.f, 0.f, 0.f, 0.f};
            if (s == q1) { d[e1 & 3] = 1.f; c[e1 & 3] = v1; }   // rare
            if (s == q2) { d[e2 & 3] = 1.f; c[e2 & 3] = v2; }   // rare
            __builtin_nontemporal_store(d, pd + s);
            __builtin_nontemporal_store(c, pc + s);
        }
    }
}

extern "C" void kernel_launch(void* const* d_in, const int* in_sizes, int n_in,
                              void* d_out, int out_size, void* d_ws, size_t ws_size,
                              hipStream_t stream) {
    (void)in_sizes; (void)n_in; (void)ws_size; (void)out_size;
    const float* x     = (const float*)d_in[0];
    const float* w     = (const float*)d_in[1];
    const float* noise = (const float*)d_in[2];
    float* out = (float*)d_out;
    char*  ws  = (char*)d_ws;

    int*    route   = (int*)   (ws + OFF_ROUTE);
    int*    pos1    = (int*)   (ws + OFF_POS1);
    int*    pos2raw = (int*)   (ws + OFF_POS2);
    int*    cnt1tot = (int*)   (ws + OFF_CNT1);
    float*  part    = (float*) (ws + OFF_PART);
    float2* g12     = (float2*)(ws + OFF_G12);

    k_gate<<<dim3(NTOK / 32), dim3(256), 0, stream>>>(
        x, w, noise, route, g12, part);
    k_pos<<<dim3(8), dim3(256), 0, stream>>>(
        route, pos1, pos2raw, cnt1tot);
    k_out<<<dim3(4097), dim3(256), 0, stream>>>(
        route, pos1, pos2raw, cnt1tot, g12, part, out);
}

// Round 9
// 799.654 us; speedup vs baseline: 1.4808x; 1.0833x over previous
//
#include <hip/hip_runtime.h>
#include <math.h>

#define NTOK 16384      // b*n = 8*2048
#define NPB  2048       // tokens per batch
#define DDIM 1024
#define NEXP 64
#define CAP  80
#define ROWF 5120       // NEXP*CAP floats per token row
#define SOUT 83886080LL // NTOK*NEXP*CAP

typedef float vf4 __attribute__((ext_vector_type(4)));

// workspace layout (bytes)
#define OFF_ROUTE  0                        // NTOK int (idx1 | idx2<<8 | keep2<<16)
#define OFF_POS1   (OFF_ROUTE + NTOK*4)     // NTOK int
#define OFF_POS2   (OFF_POS1  + NTOK*4)     // NTOK int
#define OFF_CNT1   (OFF_POS2  + NTOK*4)     // 512 int
#define OFF_PART   (OFF_CNT1  + 2048)       // 256*64 float per-block raw-gate sums
#define OFF_G12    (OFF_PART  + 65536)      // NTOK float2

// K1 (R6-proven): fused logits GEMM (64 tokens x 64 experts per block,
// 4x4/thread, register-prefetched k-tiles) + softmax + top1/top2 + renorm +
// keep2 + per-block raw-gate sums. LDS-BW-bound ~41 us (2.15 GB @ 85 B/cyc/CU).
__global__ __launch_bounds__(256) void k_gate(
    const float* __restrict__ x, const float* __restrict__ w,
    const float* __restrict__ noise,
    int* __restrict__ route, float2* __restrict__ g12,
    float* __restrict__ part)
{
    __shared__ float xs[32][68];   // xs[k][token]
    __shared__ float wl[32][64];   // wl[k][expert]
    __shared__ float lg[64][68];   // logits
    __shared__ float sG[4][64];

    const int tid  = threadIdx.x;
    const int tok0 = blockIdx.x * 64;
    const int tx = tid & 15, ty = tid >> 4;   // expert quad / token quad
    float acc[4][4] = {{0.f}};

    const float* xb = x + (size_t)tok0 * DDIM;
    const int t0 = tid >> 3, c0 = (tid & 7) * 4;   // staging coords

    // preload tile 0 into registers
    float4 px0 = *(const float4*)(xb + (size_t)t0 * DDIM + c0);
    float4 px1 = *(const float4*)(xb + (size_t)(t0 + 32) * DDIM + c0);
    float4 pw0 = ((const float4*)w)[tid];
    float4 pw1 = ((const float4*)w)[tid + 256];

    for (int k0 = 0; k0 < DDIM; k0 += 32) {
        xs[c0+0][t0] = px0.x; xs[c0+1][t0] = px0.y;
        xs[c0+2][t0] = px0.z; xs[c0+3][t0] = px0.w;
        xs[c0+0][t0+32] = px1.x; xs[c0+1][t0+32] = px1.y;
        xs[c0+2][t0+32] = px1.z; xs[c0+3][t0+32] = px1.w;
        ((float4*)wl)[tid]       = pw0;
        ((float4*)wl)[tid + 256] = pw1;
        __syncthreads();

        if (k0 + 32 < DDIM) {   // prefetch next tile while computing this one
            px0 = *(const float4*)(xb + (size_t)t0 * DDIM + k0 + 32 + c0);
            px1 = *(const float4*)(xb + (size_t)(t0 + 32) * DDIM + k0 + 32 + c0);
            const float4* wp = (const float4*)(w + (size_t)(k0 + 32) * NEXP);
            pw0 = wp[tid];
            pw1 = wp[tid + 256];
        }

        #pragma unroll
        for (int k = 0; k < 32; ++k) {
            float4 a  = *(const float4*)&xs[k][ty * 4];
            float4 bb = *(const float4*)&wl[k][tx * 4];
            float av[4] = {a.x, a.y, a.z, a.w};
            float bv[4] = {bb.x, bb.y, bb.z, bb.w};
            #pragma unroll
            for (int i = 0; i < 4; ++i)
                #pragma unroll
                for (int j = 0; j < 4; ++j)
                    acc[i][j] = fmaf(av[i], bv[j], acc[i][j]);
        }
        __syncthreads();
    }

    #pragma unroll
    for (int i = 0; i < 4; ++i)
        *(float4*)&lg[ty * 4 + i][tx * 4] =
            make_float4(acc[i][0], acc[i][1], acc[i][2], acc[i][3]);
    __syncthreads();

    const int lane = tid & 63;
    const int wv   = tid >> 6;
    float gsum_acc = 0.f;

    for (int it = 0; it < 16; ++it) {
        int t = wv * 16 + it;
        float v = lg[t][lane];

        float m = v; int mi = lane;
        #pragma unroll
        for (int off = 32; off; off >>= 1) {
            float ov = __shfl_xor(m, off, 64);
            int   oi = __shfl_xor(mi, off, 64);
            if (ov > m || (ov == m && oi < mi)) { m = ov; mi = oi; }
        }
        float v2 = (lane == mi) ? -INFINITY : v;
        float m2 = v2; int mi2 = lane;
        #pragma unroll
        for (int off = 32; off; off >>= 1) {
            float ov = __shfl_xor(m2, off, 64);
            int   oi = __shfl_xor(mi2, off, 64);
            if (ov > m2 || (ov == m2 && oi < mi2)) { m2 = ov; mi2 = oi; }
        }
        float ex = expf(v - m);
        float s = ex;
        #pragma unroll
        for (int off = 32; off; off >>= 1) s += __shfl_xor(s, off, 64);

        float inv   = 1.0f / s;
        float gate1 = inv;
        float gate2 = expf(m2 - m) * inv;
        gsum_acc += ex * inv;

        float denom = gate1 + gate2 + 1e-9f;
        float g1n = gate1 / denom;
        float g2n = gate2 / denom;

        int gt = tok0 + t;
        if (lane == 0) {
            float u = noise[gt];
            int k2 = (u < (g2n / 0.2f)) ? 1 : 0;
            route[gt] = mi | (mi2 << 8) | (k2 << 16);
            g12[gt] = make_float2(g1n, g2n);
        }
    }

    sG[wv][lane] = gsum_acc;
    __syncthreads();
    if (tid < 64)
        part[blockIdx.x * 64 + tid] =
            sG[0][tid] + sG[1][tid] + sG[2][tid] + sG[3][tid];
}

// K2: 3-phase position scan per batch (one 256-thread block per batch):
// A) per-64-token-tile expert histograms, B) exclusive prefix over tiles,
// C) positional rewrite with per-tile bases.
__global__ __launch_bounds__(256) void k_pos(
    const int* __restrict__ route,
    int* __restrict__ pos1, int* __restrict__ pos2raw,
    int* __restrict__ cnt1tot)
{
    const int b    = blockIdx.x;
    const int tid  = threadIdx.x;
    const int lane = tid & 63, wv = tid >> 6;
    __shared__ int sr[NPB];
    __shared__ int h1[32][64], h2[32][64];

    for (int i = tid; i < NPB; i += 256) sr[i] = route[b * NPB + i];
    __syncthreads();

    for (int tau = wv; tau < 32; tau += 4) {
        int c1 = 0, c2 = 0;
        const int* p = &sr[tau * 64];
        #pragma unroll 8
        for (int j = 0; j < 64; ++j) {
            int r = p[j];
            c1 += ((r & 255) == lane);
            c2 += ((r >> 16) && (((r >> 8) & 255) == lane));
        }
        h1[tau][lane] = c1; h2[tau][lane] = c2;
    }
    __syncthreads();

    if (tid < 64) {
        int run = 0;
        #pragma unroll 8
        for (int tau = 0; tau < 32; ++tau) {
            int t = h1[tau][tid]; h1[tau][tid] = run; run += t;
        }
        cnt1tot[b * NEXP + tid] = run;   // pre-capacity top1 total
    } else if (tid < 128) {
        int e = tid - 64, run = 0;
        #pragma unroll 8
        for (int tau = 0; tau < 32; ++tau) {
            int t = h2[tau][e]; h2[tau][e] = run; run += t;
        }
    }
    __syncthreads();

    for (int tau = wv; tau < 32; tau += 4) {
        int c1 = h1[tau][lane], c2 = h2[tau][lane];
        const int* p = &sr[tau * 64];
        const int gbase = b * NPB + tau * 64;
        #pragma unroll 4
        for (int j = 0; j < 64; ++j) {
            int r = p[j];
            if ((r & 255) == lane) pos1[gbase + j] = c1++;
            if ((r >> 16) && (((r >> 8) & 255) == lane)) pos2raw[gbase + j] = c2++;
        }
    }
}

// K3: single streaming pass writes BOTH halves for 4 tokens per block,
// de-interleaved (dispatch row then combine row per token) nt stores;
// zero fast-path; block 4096 computes the loss.
__global__ __launch_bounds__(256) void k_out(
    const int* __restrict__ route,
    const int* __restrict__ pos1, const int* __restrict__ pos2raw,
    const int* __restrict__ cnt1tot,
    const float2* __restrict__ g12, const float* __restrict__ part,
    float* __restrict__ out)
{
    const int tid = threadIdx.x;
    const int bid = blockIdx.x;

    if (bid == 4096) {
        __shared__ float red[4];
        float v = 0.f;
        for (int p = tid; p < 512; p += 256) {
            int b = p >> 6, e = p & 63;
            float s = 0.f;
            #pragma unroll 8
            for (int c = 0; c < 32; ++c) s += part[((b << 5) + c) * 64 + e];
            v += s * (float)cnt1tot[p];
        }
        #pragma unroll
        for (int off = 32; off; off >>= 1) v += __shfl_xor(v, off, 64);
        if ((tid & 63) == 0) red[tid >> 6] = v;
        __syncthreads();
        if (tid == 0)
            out[2 * SOUT] = (red[0] + red[1] + red[2] + red[3]) * (1.0f / 524288.0f);
        return;
    }

    const int tg = bid * 4;

    __shared__ int   se[4][2];
    __shared__ float sv[4][2];

    if (tid < 4) {
        int t = tg + tid;
        int b = t >> 11;
        int r  = route[t];
        int i1 = r & 255, i2 = (r >> 8) & 255, k2 = (r >> 16);
        float2 g = g12[t];

        int p1 = pos1[t];
        se[tid][0] = (p1 < CAP) ? (i1 * CAP + p1) : -1;
        sv[tid][0] = g.x;

        int e2 = -1;
        if (k2) {
            int m1c = min(cnt1tot[(b << 6) + i2], CAP);
            int p2  = pos2raw[t] + m1c;
            if (p2 < CAP) e2 = i2 * CAP + p2;
        }
        se[tid][1] = e2;
        sv[tid][1] = g.y;
    }
    __syncthreads();

    vf4* dbase = (vf4*)(out + (size_t)tg * ROWF);
    vf4* cbase = (vf4*)(out + (size_t)SOUT + (size_t)tg * ROWF);
    #pragma unroll
    for (int t = 0; t < 4; ++t) {
        const int   e1 = se[t][0], e2 = se[t][1];
        const float v1 = sv[t][0], v2 = sv[t][1];
        const int   q1 = e1 >> 2, q2 = e2 >> 2;   // vf4 slot containing e1/e2
        vf4* pd = dbase + (size_t)t * (ROWF / 4);
        vf4* pc = cbase + (size_t)t * (ROWF / 4);
        #pragma unroll
        for (int s5 = 0; s5 < 5; ++s5) {          // dispatch row (5 x 256 slots)
            int s = s5 * 256 + tid;
            vf4 d = {0.f, 0.f, 0.f, 0.f};
            if (s == q1) d[e1 & 3] = 1.f;
            if (s == q2) d[e2 & 3] = 1.f;
            __builtin_nontemporal_store(d, pd + s);
        }
        #pragma unroll
        for (int s5 = 0; s5 < 5; ++s5) {          // combine row
            int s = s5 * 256 + tid;
            vf4 c = {0.f, 0.f, 0.f, 0.f};
            if (s == q1) c[e1 & 3] = v1;
            if (s == q2) c[e2 & 3] = v2;
            __builtin_nontemporal_store(c, pc + s);
        }
    }
}

extern "C" void kernel_launch(void* const* d_in, const int* in_sizes, int n_in,
                              void* d_out, int out_size, void* d_ws, size_t ws_size,
                              hipStream_t stream) {
    (void)in_sizes; (void)n_in; (void)ws_size; (void)out_size;
    const float* x     = (const float*)d_in[0];
    const float* w     = (const float*)d_in[1];
    const float* noise = (const float*)d_in[2];
    float* out = (float*)d_out;
    char*  ws  = (char*)d_ws;

    int*    route   = (int*)   (ws + OFF_ROUTE);
    int*    pos1    = (int*)   (ws + OFF_POS1);
    int*    pos2raw = (int*)   (ws + OFF_POS2);
    int*    cnt1tot = (int*)   (ws + OFF_CNT1);
    float*  part    = (float*) (ws + OFF_PART);
    float2* g12     = (float2*)(ws + OFF_G12);

    k_gate<<<dim3(NTOK / 64), dim3(256), 0, stream>>>(
        x, w, noise, route, g12, part);
    k_pos<<<dim3(8), dim3(256), 0, stream>>>(
        route, pos1, pos2raw, cnt1tot);
    k_out<<<dim3(4097), dim3(256), 0, stream>>>(
        route, pos1, pos2raw, cnt1tot, g12, part, out);
}